// Round 7
// baseline (213.510 us; speedup 1.0000x reference)
//
#include <hip/hip_runtime.h>

// GRU (B=4096, T=512, I=1, H=32) + FC(32->12): per-CU fork-join MFMA design.
//
// 256 blocks x 256 threads (4 waves) = 1 block/CU; each block owns 16 batch
// rows for all 512 timesteps (sequences independent -> no inter-block sync).
// Per step:
//   phase 1 (wave 0): preact[16x96] = h_f16[16x32] @ w_hh^T via 12x
//       v_mfma_f32_16x16x16f16 (A: row=lane%16,k=4*(lane/16)+i;
//       B: k=4*(lane/16)+i,col=lane%16; D: col=lane%16,row=4*(lane/16)+reg),
//       f32 result -> LDS pre[96][20].
//   phase 2 (all 4 waves): gate nonlinearities for 4 rows/wave, 2 rows/lane
//       (u=lane&31) -> transcendentals run on all 4 SIMDs of the CU.
//       h kept f32 in registers (recurrence never rounded); f16 copy -> LDS
//       as next step's A operand.
// x[16 rows][512] staged in LDS once (global traffic: read-once).
// exp folding: r,z rows scaled by -log2e, n rows by +2log2e (weights, biases,
// x-terms all scaled) so gates use raw v_exp_f32/v_rcp_f32.

namespace {

typedef _Float16 f16;
typedef _Float16 f16x4 __attribute__((ext_vector_type(4)));
typedef float    f32x4 __attribute__((ext_vector_type(4)));

constexpr int kT  = 512;
constexpr int kXP = 516;   // x_s row pitch (f32): 516*4 % 16 == 0, broadcast reads
constexpr int kPP = 20;    // pre row pitch (f32): pad 16->20 vs bank aliasing
constexpr int kHP = 36;    // hl  row pitch (f16): 72B rows -> conflict-free A reads
constexpr float kL2E = 1.4426950408889634f;

__device__ __forceinline__ float fast_exp2(float a) {
#if __has_builtin(__builtin_amdgcn_exp2f)
    return __builtin_amdgcn_exp2f(a);
#else
    return exp2f(a);
#endif
}
__device__ __forceinline__ float fast_rcp(float a) {
#if __has_builtin(__builtin_amdgcn_rcpf)
    return __builtin_amdgcn_rcpf(a);
#else
    return 1.0f / a;
#endif
}

__global__ __launch_bounds__(256)
__attribute__((amdgpu_waves_per_eu(1, 1)))
void gru_mfma(
    const float* __restrict__ x,      // [4096, 512]
    const float* __restrict__ w_ih,   // [96]
    const float* __restrict__ w_hh,   // [96, 32]
    const float* __restrict__ b_ih,   // [96]
    const float* __restrict__ b_hh,   // [96]
    const float* __restrict__ fc_w,   // [12, 32]
    const float* __restrict__ fc_b,   // [12]
    float* __restrict__ out)          // [4096, 12]
{
    __shared__ float xs[16 * kXP];    // staged x, reused as hf[16][33] at end
    __shared__ float pre[96 * kPP];   // MFMA preactivations [gate][row]
    __shared__ f16   hl[16 * kHP];    // f16 h, A-operand layout friendly

    const int tid  = threadIdx.x;
    const int lane = tid & 63;
    const int wave = tid >> 6;
    const int blk  = blockIdx.x;

    // ---- stage x: block's 16 rows are one contiguous 32KB chunk ----
    {
        const float4* xg = reinterpret_cast<const float4*>(x + (size_t)blk * 16 * kT);
#pragma unroll
        for (int k = 0; k < 8; ++k) {
            const int i   = tid + k * 256;      // float4 index over 2048
            const float4 v = xg[i];
            const int row = i >> 7;             // / (512/4)
            const int col = (i & 127) << 2;
            *reinterpret_cast<float4*>(&xs[row * kXP + col]) = v;
        }
    }
    // ---- zero hl (h0 = 0) ----
    {
        unsigned int* hz = reinterpret_cast<unsigned int*>(hl);
        for (int i = tid; i < 16 * kHP / 2; i += 256) hz[i] = 0u;
    }

    // ---- MFMA B-fragments (w_hh^T), scale-folded, loaded by every wave ----
    const int lc = lane & 15;    // col within tile
    const int lg = lane >> 2 >> 2; // lane>>4
    f16x4 wf[6][2];
#pragma unroll
    for (int nt = 0; nt < 6; ++nt) {
        const float s = (nt < 4) ? -kL2E : 2.0f * kL2E;
#pragma unroll
        for (int kt = 0; kt < 2; ++kt) {
            f16x4 f;
#pragma unroll
            for (int v = 0; v < 4; ++v)
                f[v] = (f16)(s * w_hh[(nt * 16 + lc) * 32 + kt * 16 + lg * 4 + v]);
            wf[nt][kt] = f;
        }
    }

    // ---- gate-phase constants: unit u, rows r0, r0+1 ----
    const int u  = lane & 31;
    const int r0 = wave * 4 + (lane >> 5) * 2;
    const float wihr  = -kL2E * w_ih[u];
    const float wihz  = -kL2E * w_ih[u + 32];
    const float wihn  = 2.0f * kL2E * w_ih[u + 64];
    const float biasr = -kL2E * (b_ih[u] + b_hh[u]);
    const float biasz = -kL2E * (b_ih[u + 32] + b_hh[u + 32]);
    const float bin   = 2.0f * kL2E * b_ih[u + 64];
    const float bhn   = 2.0f * kL2E * b_hh[u + 64];

    float h0 = 0.0f, h1 = 0.0f;

    const f16* aptr0 = &hl[lc * kHP + lg * 4];        // A frag, kt=0
    const f16* aptr1 = aptr0 + 16;                    // A frag, kt=1

    __syncthreads();

    for (int t = 0; t < kT; ++t) {
        // ---- phase 1: wave 0 computes preact[16x96] via MFMA ----
        if (wave == 0) {
            const f16x4 a0 = *reinterpret_cast<const f16x4*>(aptr0);
            const f16x4 a1 = *reinterpret_cast<const f16x4*>(aptr1);
#pragma unroll
            for (int nt = 0; nt < 6; ++nt) {
                f32x4 acc = {0.0f, 0.0f, 0.0f, 0.0f};
                acc = __builtin_amdgcn_mfma_f32_16x16x16f16(a0, wf[nt][0], acc, 0, 0, 0);
                acc = __builtin_amdgcn_mfma_f32_16x16x16f16(a1, wf[nt][1], acc, 0, 0, 0);
                *reinterpret_cast<f32x4*>(&pre[(nt * 16 + lc) * kPP + lg * 4]) = acc;
            }
        }
        __syncthreads();

        // ---- phase 2: all waves, gate math for rows r0, r0+1, unit u ----
        const float xt0 = xs[r0 * kXP + t];
        const float xt1 = xs[(r0 + 1) * kXP + t];
        const float2 pr = *reinterpret_cast<const float2*>(&pre[u * kPP + r0]);
        const float2 pz = *reinterpret_cast<const float2*>(&pre[(u + 32) * kPP + r0]);
        const float2 pn = *reinterpret_cast<const float2*>(&pre[(u + 64) * kPP + r0]);
        {
            const float ar = pr.x + fmaf(xt0, wihr, biasr);
            const float az = pz.x + fmaf(xt0, wihz, biasz);
            const float an = pn.x + bhn;
            const float inn = fmaf(xt0, wihn, bin);
            const float r = fast_rcp(1.0f + fast_exp2(ar));
            const float z = fast_rcp(1.0f + fast_exp2(az));
            const float n = fmaf(-2.0f, fast_rcp(1.0f + fast_exp2(fmaf(r, an, inn))), 1.0f);
            h0 = fmaf(z, h0 - n, n);
        }
        {
            const float ar = pr.y + fmaf(xt1, wihr, biasr);
            const float az = pz.y + fmaf(xt1, wihz, biasz);
            const float an = pn.y + bhn;
            const float inn = fmaf(xt1, wihn, bin);
            const float r = fast_rcp(1.0f + fast_exp2(ar));
            const float z = fast_rcp(1.0f + fast_exp2(az));
            const float n = fmaf(-2.0f, fast_rcp(1.0f + fast_exp2(fmaf(r, an, inn))), 1.0f);
            h1 = fmaf(z, h1 - n, n);
        }
        hl[r0 * kHP + u]       = (f16)h0;
        hl[(r0 + 1) * kHP + u] = (f16)h1;
        __syncthreads();
    }

    // ---- FC epilogue: hf = final h (f32) in reused xs, then 16x12 dots ----
    float* hf = xs;   // pitch 33, all xs reads are complete
    hf[r0 * 33 + u]       = h0;
    hf[(r0 + 1) * 33 + u] = h1;
    __syncthreads();
    if (tid < 192) {
        const int row = tid / 12, o = tid % 12;
        float acc = fc_b[o];
#pragma unroll
        for (int k = 0; k < 32; ++k)
            acc = fmaf(fc_w[o * 32 + k], hf[row * 33 + k], acc);
        out[((size_t)blk * 16 + row) * 12 + o] = acc;
    }
}

}  // namespace

extern "C" void kernel_launch(void* const* d_in, const int* in_sizes, int n_in,
                              void* d_out, int out_size, void* d_ws, size_t ws_size,
                              hipStream_t stream) {
    const float* x    = (const float*)d_in[0];
    const float* w_ih = (const float*)d_in[1];
    const float* w_hh = (const float*)d_in[2];
    const float* b_ih = (const float*)d_in[3];
    const float* b_hh = (const float*)d_in[4];
    const float* fc_w = (const float*)d_in[5];
    const float* fc_b = (const float*)d_in[6];
    float* out = (float*)d_out;

    dim3 grid(256);    // 4096 rows / 16 rows per block
    dim3 block(256);   // 4 waves: wave 0 = MFMA, all waves = gates
    gru_mfma<<<grid, block, 0, stream>>>(x, w_ih, w_hh, b_ih, b_hh, fc_w, fc_b, out);
}